// Round 5
// baseline (1198.196 us; speedup 1.0000x reference)
//
#include <hip/hip_runtime.h>
#include <math.h>

#define NB 16    // batch
#define SS 256   // spatial size (H = W = 256)
#define DV 32    // channels
#define MM 12    // w-dim (j) modes kept
#define MK 24    // h-dim (iy) modes kept (0..11 and 244..255)
#define LL 4     // layers
#define TWO_PI_N 0.024543692606170259679f   // 2*pi/256

// Workspace (floats):
//   h   : [NB][DV][SS][SS]            134 MB, in-place per layer
//   A   : [NB][MM][DV][SS(iy)][2]     12.6 MB  (row-DFT of h)
//   F   : [NB][MM][DV][MK][2]          1.2 MB  (mixed spectral coeffs, pre-scaled)
//   twT : [SS][MM][2]                  24 KB   (cos, -sin) of 2*pi*ky*j/256

// ------------------------------------------------------------- twiddle init
__global__ __launch_bounds__(256) void k_twinit(float* __restrict__ twT)
{
    int j = threadIdx.x;
    #pragma unroll
    for (int k = 0; k < MM; ++k) {
        float ang = TWO_PI_N * (float)((k * j) & 255);
        float s, c; sincosf(ang, &s, &c);
        twT[j * (MM * 2) + 2 * k]     = c;
        twT[j * (MM * 2) + 2 * k + 1] = -s;
    }
}

// ---------------------------------------------------------------- lifting
__global__ __launch_bounds__(256) void k_lift(const float* __restrict__ x,
        const float* __restrict__ p_w, const float* __restrict__ p_b,
        float* __restrict__ h)
{
    int tid = threadIdx.x;
    int b = blockIdx.x >> 8, iy = blockIdx.x & 255;
    float xv = x[((size_t)b * SS + iy) * SS + tid];
    float gy = -1.f + 2.f * (float)iy  * (1.f / 255.f);
    float gx = -1.f + 2.f * (float)tid * (1.f / 255.f);
    float* hb = h + ((size_t)b * DV * SS + iy) * SS + tid;
    #pragma unroll
    for (int c = 0; c < DV; ++c)
        hb[(size_t)c * SS * SS] = p_w[3*c] * xv + p_w[3*c+1] * gy
                                + p_w[3*c+2] * gx + p_b[c];
}

// ------------------------------------------------- forward row (j) DFT, 12 modes
// block = (b,c); lane = iy; thread owns its entire row. Radix-2 over j/j+128:
// A[ky] = sum_{j<128} (v_j + (-1)^ky v_{j+128}) e^{-i th}. Twiddles via
// block-uniform global loads (compiler scalarizes to s_load / K$).
__global__ __launch_bounds__(256, 4) void k_rowdft(const float* __restrict__ h,
        const float* __restrict__ twT, float* __restrict__ A)
{
    int tid = threadIdx.x;
    int b = blockIdx.x >> 5, c = blockIdx.x & 31;

    const float4* hr = (const float4*)(h + ((size_t)blockIdx.x * SS + tid) * SS);
    float ar[MM], ai[MM];
    #pragma unroll
    for (int k = 0; k < MM; ++k) { ar[k] = 0.f; ai[k] = 0.f; }

    #pragma unroll 2
    for (int j4 = 0; j4 < 32; ++j4) {
        float4 va = hr[j4];
        float4 vb = hr[j4 + 32];
        float hp[4] = {va.x + vb.x, va.y + vb.y, va.z + vb.z, va.w + vb.w};
        float hm[4] = {va.x - vb.x, va.y - vb.y, va.z - vb.z, va.w - vb.w};
        #pragma unroll
        for (int u = 0; u < 4; ++u) {
            const float* twj = twT + (size_t)(4 * j4 + u) * (MM * 2);  // uniform
            #pragma unroll
            for (int k = 0; k < 6; ++k) {
                ar[2*k]   += hp[u] * twj[4*k];
                ai[2*k]   += hp[u] * twj[4*k + 1];
                ar[2*k+1] += hm[u] * twj[4*k + 2];
                ai[2*k+1] += hm[u] * twj[4*k + 3];
            }
        }
    }
    #pragma unroll
    for (int ky = 0; ky < MM; ++ky) {
        size_t o = ((((size_t)b * MM + ky) * DV + c) * SS + tid) * 2;
        float2 val; val.x = ar[ky]; val.y = ai[ky];
        *(float2*)&A[o] = val;                      // coalesced over iy
    }
}

// --------------------------- kx (iy) DFT + complex channel mix -> F (pre-scaled)
__global__ __launch_bounds__(256) void k_mix(const float* __restrict__ A,
        const float* __restrict__ w1r, const float* __restrict__ w1i,
        const float* __restrict__ w2r, const float* __restrict__ w2i,
        float* __restrict__ F, int l)
{
    __shared__ float twcs[SS * 2];             // (cos, sin) of +2*pi*t/256
    __shared__ float Fin[DV][MK * 2 + 2];
    int tid = threadIdx.x;
    int b = blockIdx.x / MM, ky = blockIdx.x % MM;
    {
        float ang = TWO_PI_N * (float)tid;
        float s, c; sincosf(ang, &s, &c);
        twcs[2 * tid] = c; twcs[2 * tid + 1] = s;
    }
    __syncthreads();

    int c = tid >> 3, set = tid & 7;
    const float2* Ap = (const float2*)(A + ((((size_t)b * MM + ky) * DV + c) * SS) * 2);

    float fr[3], fi[3], pc[3], ps[3], sc[3], ssn[3];
    int f[3];
    #pragma unroll
    for (int k = 0; k < 3; ++k) {
        int m = set + 8 * k;
        f[k] = (m < MM) ? m : (232 + m);       // 244..255 for m >= 12
        sc[k] = twcs[2 * f[k]]; ssn[k] = twcs[2 * f[k] + 1];
        fr[k] = fi[k] = 0.f; pc[k] = 1.f; ps[k] = 0.f;
    }
    for (int iy = 0; iy < SS; ++iy) {
        if ((iy & 63) == 0) {                  // re-anchor: kills phasor drift
            #pragma unroll
            for (int k = 0; k < 3; ++k) {
                int t = (f[k] * iy) & 255;
                pc[k] = twcs[2 * t]; ps[k] = twcs[2 * t + 1];
            }
        }
        float2 a = Ap[iy];
        #pragma unroll
        for (int k = 0; k < 3; ++k) {
            fr[k] += a.x * pc[k] + a.y * ps[k];   // A * e^{-i th}
            fi[k] += a.y * pc[k] - a.x * ps[k];
            float np = pc[k] * sc[k] - ps[k] * ssn[k];
            float nq = pc[k] * ssn[k] + ps[k] * sc[k];
            pc[k] = np; ps[k] = nq;
        }
    }
    #pragma unroll
    for (int k = 0; k < 3; ++k) {
        int m = set + 8 * k;
        Fin[c][2 * m] = fr[k]; Fin[c][2 * m + 1] = fi[k];
    }
    __syncthreads();

    int o = c;
    float scale = ((ky == 0) ? 1.0f : 2.0f) * (1.0f / 65536.0f);
    #pragma unroll
    for (int k = 0; k < 3; ++k) {
        int m = set + 8 * k;
        const float* Wr; const float* Wi; int xm;
        if (m < MM) { Wr = w1r; Wi = w1i; xm = m; }
        else        { Wr = w2r; Wi = w2i; xm = m - MM; }
        float orr = 0.f, oii = 0.f;
        for (int i = 0; i < DV; ++i) {
            float gr = Fin[i][2 * m], gi = Fin[i][2 * m + 1];
            size_t wi = ((size_t)(l * DV + i) * DV + o) * (MM * MM) + xm * MM + ky;
            float wr = Wr[wi], wim = Wi[wi];
            orr += gr * wr - gi * wim;
            oii += gr * wim + gi * wr;
        }
        size_t off = ((((size_t)b * MM + ky) * DV + o) * MK + m) * 2;
        F[off] = orr * scale; F[off + 1] = oii * scale;
    }
}

// ----------------- pointwise: h = relu(conv1x1(h) + invDFT(F)), in place.
// block = (b,iy).
// Phase A: gS[co][ky] = inverse iy-DFT of F (wave-uniform itw twiddles).
// Phase B: sS[co][j]  = Re(sum_ky gS e^{+i 2pi ky j/256}) via the quadrant
//          trick (j+64q multiplies by i^{ky q}); twiddles from global twT (L1).
// Conv:    thread=j: acc = bias + sS[co][j] + sum_ci w*hval (s_load weights).
template<int FINAL>
__global__ __launch_bounds__(256, 4) void k_pt(float* __restrict__ h,
        const float* __restrict__ F, const float* __restrict__ twT,
        const float* __restrict__ ws_w, const float* __restrict__ ws_b,
        const float* __restrict__ q_w, const float* __restrict__ q_b,
        float* __restrict__ out, int l)
{
    __shared__ float gS[DV][28];        // [co][2*ky], padded row (112 B)
    __shared__ float sS[DV][SS + 1];    // spectral spatial contribution
    __shared__ float itw[MK * 2];       // e^{+i 2pi f_m iy/256}
    int tid = threadIdx.x;
    int b = blockIdx.x >> 8, iy = blockIdx.x & 255;

    // issue hval loads early (latency hidden behind phases A/B)
    float* hb = h + ((size_t)b * DV * SS + iy) * SS + tid;
    float hval[DV];
    #pragma unroll
    for (int cc = 0; cc < DV; ++cc)
        hval[cc] = hb[(size_t)cc * SS * SS];

    if (tid < MK) {
        int f = (tid < MM) ? tid : (232 + tid);
        float ang = TWO_PI_N * (float)((f * iy) & 255);
        float s, c; sincosf(ang, &s, &c);
        itw[2 * tid] = c; itw[2 * tid + 1] = s;
    }
    __syncthreads();

    // ---- phase A
    for (int idx = tid; idx < DV * MM; idx += 256) {
        int co = idx & 31, ky = idx >> 5;
        const float2* Fp = (const float2*)(F + ((((size_t)b * MM + ky) * DV + co) * MK) * 2);
        float gr = 0.f, gi = 0.f;
        #pragma unroll
        for (int m = 0; m < MK; ++m) {
            float2 fv = Fp[m];
            float ic = itw[2 * m], is = itw[2 * m + 1];
            gr += fv.x * ic - fv.y * is;
            gi += fv.x * is + fv.y * ic;
        }
        gS[co][2 * ky] = gr; gS[co][2 * ky + 1] = gi;
    }
    __syncthreads();

    // ---- phase B
    {
        int co = tid >> 3, bj0 = (tid & 7) * 8;
        float G[MM * 2];
        #pragma unroll
        for (int q = 0; q < 6; ++q)
            *(float4*)&G[4 * q] = *(const float4*)&gS[co][4 * q];

        #pragma unroll 1
        for (int u = 0; u < 8; ++u) {
            int j = bj0 + u;
            const float4* twj = (const float4*)(twT + (size_t)j * (MM * 2));
            float a0 = 0.f, a1 = 0.f, a2 = 0.f, a3 = 0.f;
            #pragma unroll
            for (int q = 0; q < 6; ++q) {
                float4 w = twj[q];   // (c,-s) for ky=2q then ky=2q+1
                #pragma unroll
                for (int e = 0; e < 2; ++e) {
                    int ky = 2 * q + e;
                    float cc = e ? w.z : w.x, ms = e ? w.w : w.y;
                    float gr = G[2 * ky], gi = G[2 * ky + 1];
                    float tr = gr * cc + gi * ms;      // Re(G e^{+i th})
                    float ti = gi * cc - gr * ms;      // Im(G e^{+i th})
                    int r = ky & 3;
                    a0 += tr;
                    a1 += (r == 0) ? tr : (r == 1) ? -ti : (r == 2) ? -tr : ti;
                    a2 += (ky & 1) ? -tr : tr;
                    a3 += (r == 0) ? tr : (r == 1) ? ti : (r == 2) ? -tr : -ti;
                }
            }
            sS[co][j]       = a0;
            sS[co][j + 64]  = a1;
            sS[co][j + 128] = a2;
            sS[co][j + 192] = a3;
        }
    }
    __syncthreads();

    // ---- conv + combine
    const float* wsw = ws_w + (size_t)l * DV * DV;
    const float* wsb = ws_b + (size_t)l * DV;
    float oacc = FINAL ? q_b[0] : 0.f;

    #pragma unroll 4
    for (int co = 0; co < DV; ++co) {
        float acc = wsb[co] + sS[co][tid];
        #pragma unroll
        for (int ci = 0; ci < DV; ++ci)
            acc += wsw[co * DV + ci] * hval[ci];   // uniform -> s_load
        if (FINAL) oacc += q_w[co] * acc;
        else       hb[(size_t)co * SS * SS] = fmaxf(acc, 0.f);
    }
    if (FINAL) out[((size_t)b * SS + iy) * SS + tid] = oacc;
}

extern "C" void kernel_launch(void* const* d_in, const int* in_sizes, int n_in,
                              void* d_out, int out_size, void* d_ws, size_t ws_size,
                              hipStream_t stream)
{
    const float* x    = (const float*)d_in[0];
    const float* p_w  = (const float*)d_in[1];
    const float* p_b  = (const float*)d_in[2];
    const float* ws_w = (const float*)d_in[3];
    const float* ws_b = (const float*)d_in[4];
    const float* w1r  = (const float*)d_in[5];
    const float* w1i  = (const float*)d_in[6];
    const float* w2r  = (const float*)d_in[7];
    const float* w2i  = (const float*)d_in[8];
    const float* q_w  = (const float*)d_in[9];
    const float* q_b  = (const float*)d_in[10];
    float* out = (float*)d_out;

    float* h   = (float*)d_ws;
    float* A   = h + (size_t)NB * DV * SS * SS;
    float* F   = A + (size_t)NB * MM * DV * SS * 2;
    float* twT = F + (size_t)NB * MM * DV * MK * 2;

    dim3 blk(256);
    k_twinit<<<1, blk, 0, stream>>>(twT);
    k_lift<<<NB * SS, blk, 0, stream>>>(x, p_w, p_b, h);
    for (int l = 0; l < LL; ++l) {
        k_rowdft<<<NB * DV, blk, 0, stream>>>(h, twT, A);
        k_mix<<<NB * MM, blk, 0, stream>>>(A, w1r, w1i, w2r, w2i, F, l);
        if (l < LL - 1)
            k_pt<0><<<NB * SS, blk, 0, stream>>>(h, F, twT, ws_w, ws_b,
                                                 nullptr, nullptr, nullptr, l);
        else
            k_pt<1><<<NB * SS, blk, 0, stream>>>(h, F, twT, ws_w, ws_b,
                                                 q_w, q_b, out, l);
    }
}

// Round 6
// 940.921 us; speedup vs baseline: 1.2734x; 1.2734x over previous
//
#include <hip/hip_runtime.h>
#include <math.h>

#define NB 16    // batch
#define SS 256   // spatial size (H = W = 256)
#define DV 32    // channels
#define MM 12    // w-dim (j) modes kept
#define MK 24    // h-dim (iy) modes kept (0..11 and 244..255)
#define LL 4     // layers
#define TWO_PI_N 0.024543692606170259679f   // 2*pi/256

// Workspace (floats):
//   h   : [NB][DV][SS][SS]            134 MB, in-place per layer
//   A   : [NB][MM][DV][SS(iy)][2]     12.6 MB  (row-DFT of h)
//   F   : [NB][MM][DV][MK][2]          1.2 MB  (mixed spectral coeffs, pre-scaled)
//   g   : [NB][SS(iy)][DV][MM][2]     12.6 MB  (per-row spectral coeffs)
//   twT : [SS][MM][2]                  24 KB   (cos, -sin) of 2*pi*ky*j/256

// ------------------------------------------------------------- twiddle init
__global__ __launch_bounds__(256) void k_twinit(float* __restrict__ twT)
{
    int j = threadIdx.x;
    #pragma unroll
    for (int k = 0; k < MM; ++k) {
        float ang = TWO_PI_N * (float)((k * j) & 255);
        float s, c; sincosf(ang, &s, &c);
        twT[j * (MM * 2) + 2 * k]     = c;
        twT[j * (MM * 2) + 2 * k + 1] = -s;
    }
}

// ---------------------------------------------------------------- lifting
__global__ __launch_bounds__(256) void k_lift(const float* __restrict__ x,
        const float* __restrict__ p_w, const float* __restrict__ p_b,
        float* __restrict__ h)
{
    int tid = threadIdx.x;
    int b = blockIdx.x >> 8, iy = blockIdx.x & 255;
    float xv = x[((size_t)b * SS + iy) * SS + tid];
    float gy = -1.f + 2.f * (float)iy  * (1.f / 255.f);
    float gx = -1.f + 2.f * (float)tid * (1.f / 255.f);
    float* hb = h + ((size_t)b * DV * SS + iy) * SS + tid;
    #pragma unroll
    for (int c = 0; c < DV; ++c)
        hb[(size_t)c * SS * SS] = p_w[3*c] * xv + p_w[3*c+1] * gy
                                + p_w[3*c+2] * gx + p_b[c];
}

// ------------------------------------------------- forward row (j) DFT, 12 modes
// block = (b,c); lane = iy; thread owns its entire row. Radix-2 over j/j+128:
// A[ky] = sum_{j<128} (v_j + (-1)^ky v_{j+128}) e^{-i th}. Twiddles via
// block-uniform global loads (compiler scalarizes to s_load / K$).
__global__ __launch_bounds__(256, 4) void k_rowdft(const float* __restrict__ h,
        const float* __restrict__ twT, float* __restrict__ A)
{
    int tid = threadIdx.x;
    int b = blockIdx.x >> 5, c = blockIdx.x & 31;

    const float4* hr = (const float4*)(h + ((size_t)blockIdx.x * SS + tid) * SS);
    float ar[MM], ai[MM];
    #pragma unroll
    for (int k = 0; k < MM; ++k) { ar[k] = 0.f; ai[k] = 0.f; }

    #pragma unroll 2
    for (int j4 = 0; j4 < 32; ++j4) {
        float4 va = hr[j4];
        float4 vb = hr[j4 + 32];
        float hp[4] = {va.x + vb.x, va.y + vb.y, va.z + vb.z, va.w + vb.w};
        float hm[4] = {va.x - vb.x, va.y - vb.y, va.z - vb.z, va.w - vb.w};
        #pragma unroll
        for (int u = 0; u < 4; ++u) {
            const float* twj = twT + (size_t)(4 * j4 + u) * (MM * 2);  // uniform
            #pragma unroll
            for (int k = 0; k < 6; ++k) {
                ar[2*k]   += hp[u] * twj[4*k];
                ai[2*k]   += hp[u] * twj[4*k + 1];
                ar[2*k+1] += hm[u] * twj[4*k + 2];
                ai[2*k+1] += hm[u] * twj[4*k + 3];
            }
        }
    }
    #pragma unroll
    for (int ky = 0; ky < MM; ++ky) {
        size_t o = ((((size_t)b * MM + ky) * DV + c) * SS + tid) * 2;
        float2 val; val.x = ar[ky]; val.y = ai[ky];
        *(float2*)&A[o] = val;                      // coalesced over iy
    }
}

// --------------------------- kx (iy) DFT + complex channel mix -> F (pre-scaled)
__global__ __launch_bounds__(256) void k_mix(const float* __restrict__ A,
        const float* __restrict__ w1r, const float* __restrict__ w1i,
        const float* __restrict__ w2r, const float* __restrict__ w2i,
        float* __restrict__ F, int l)
{
    __shared__ float twcs[SS * 2];             // (cos, sin) of +2*pi*t/256
    __shared__ float Fin[DV][MK * 2 + 2];
    int tid = threadIdx.x;
    int b = blockIdx.x / MM, ky = blockIdx.x % MM;
    {
        float ang = TWO_PI_N * (float)tid;
        float s, c; sincosf(ang, &s, &c);
        twcs[2 * tid] = c; twcs[2 * tid + 1] = s;
    }
    __syncthreads();

    int c = tid >> 3, set = tid & 7;
    const float2* Ap = (const float2*)(A + ((((size_t)b * MM + ky) * DV + c) * SS) * 2);

    float fr[3], fi[3], pc[3], ps[3], sc[3], ssn[3];
    int f[3];
    #pragma unroll
    for (int k = 0; k < 3; ++k) {
        int m = set + 8 * k;
        f[k] = (m < MM) ? m : (232 + m);       // 244..255 for m >= 12
        sc[k] = twcs[2 * f[k]]; ssn[k] = twcs[2 * f[k] + 1];
        fr[k] = fi[k] = 0.f; pc[k] = 1.f; ps[k] = 0.f;
    }
    for (int iy = 0; iy < SS; ++iy) {
        if ((iy & 63) == 0) {                  // re-anchor: kills phasor drift
            #pragma unroll
            for (int k = 0; k < 3; ++k) {
                int t = (f[k] * iy) & 255;
                pc[k] = twcs[2 * t]; ps[k] = twcs[2 * t + 1];
            }
        }
        float2 a = Ap[iy];
        #pragma unroll
        for (int k = 0; k < 3; ++k) {
            fr[k] += a.x * pc[k] + a.y * ps[k];   // A * e^{-i th}
            fi[k] += a.y * pc[k] - a.x * ps[k];
            float np = pc[k] * sc[k] - ps[k] * ssn[k];
            float nq = pc[k] * ssn[k] + ps[k] * sc[k];
            pc[k] = np; ps[k] = nq;
        }
    }
    #pragma unroll
    for (int k = 0; k < 3; ++k) {
        int m = set + 8 * k;
        Fin[c][2 * m] = fr[k]; Fin[c][2 * m + 1] = fi[k];
    }
    __syncthreads();

    int o = c;
    float scale = ((ky == 0) ? 1.0f : 2.0f) * (1.0f / 65536.0f);
    #pragma unroll
    for (int k = 0; k < 3; ++k) {
        int m = set + 8 * k;
        const float* Wr; const float* Wi; int xm;
        if (m < MM) { Wr = w1r; Wi = w1i; xm = m; }
        else        { Wr = w2r; Wi = w2i; xm = m - MM; }
        float orr = 0.f, oii = 0.f;
        for (int i = 0; i < DV; ++i) {
            float gr = Fin[i][2 * m], gi = Fin[i][2 * m + 1];
            size_t wi = ((size_t)(l * DV + i) * DV + o) * (MM * MM) + xm * MM + ky;
            float wr = Wr[wi], wim = Wi[wi];
            orr += gr * wr - gi * wim;
            oii += gr * wim + gi * wr;
        }
        size_t off = ((((size_t)b * MM + ky) * DV + o) * MK + m) * 2;
        F[off] = orr * scale; F[off + 1] = oii * scale;
    }
}

// -------------------- inverse iy-DFT: F -> g[b][iy][co][ky] (complex)
// block = (b,iy), 384 threads = one (co,ky) pair each. Writes are exactly
// contiguous (offset = 2*tid). Tiny kernel; F is L2/L3-resident.
__global__ __launch_bounds__(384) void k_inv1(const float* __restrict__ F,
        float* __restrict__ g)
{
    __shared__ float itw[MK * 2];       // e^{+i 2pi f_m iy/256}
    int tid = threadIdx.x;
    int b = blockIdx.x >> 8, iy = blockIdx.x & 255;
    if (tid < MK) {
        int f = (tid < MM) ? tid : (232 + tid);
        float ang = TWO_PI_N * (float)((f * iy) & 255);
        float s, c; sincosf(ang, &s, &c);
        itw[2 * tid] = c; itw[2 * tid + 1] = s;
    }
    __syncthreads();

    int co = tid / MM, ky = tid % MM;   // tid in [0,384)
    const float2* Fp = (const float2*)(F + ((((size_t)b * MM + ky) * DV + co) * MK) * 2);
    float gr = 0.f, gi = 0.f;
    #pragma unroll
    for (int m = 0; m < MK; ++m) {
        float2 fv = Fp[m];
        float ic = itw[2 * m], is = itw[2 * m + 1];
        gr += fv.x * ic - fv.y * is;
        gi += fv.x * is + fv.y * ic;
    }
    size_t o = ((size_t)(b * SS + iy) * DV + co) * (MM * 2) + 2 * ky;  // = base + 2*tid
    g[o] = gr; g[o + 1] = gi;
}

// ----------------- pointwise: h = relu(conv1x1(h) + invDFT(F)), in place.
// block = (b,iy), thread = j. NO LDS, NO barriers. All per-block coefficients
// (g row, conv weights, biases) are block-uniform __restrict__ global loads
// -> scalarized to s_load (K$). Per-thread: 32co x (32 conv + 24 spectral) fmac.
template<int FINAL>
__global__ __launch_bounds__(256, 4) void k_pt(float* __restrict__ h,
        const float* __restrict__ g, const float* __restrict__ ws_w,
        const float* __restrict__ ws_b, const float* __restrict__ q_w,
        const float* __restrict__ q_b, float* __restrict__ out, int l)
{
    int tid = threadIdx.x;
    int b = blockIdx.x >> 8, iy = blockIdx.x & 255;

    float* hb = h + ((size_t)b * DV * SS + iy) * SS + tid;
    float hval[DV];
    #pragma unroll
    for (int cc = 0; cc < DV; ++cc)
        hval[cc] = hb[(size_t)cc * SS * SS];

    float cs[MM], sn[MM];               // e^{+i 2pi ky j/256}, j = tid
    #pragma unroll
    for (int ky = 0; ky < MM; ++ky) {
        float ang = TWO_PI_N * (float)((ky * tid) & 255);
        sincosf(ang, &sn[ky], &cs[ky]);
    }

    const float* gp  = g + ((size_t)(b * SS + iy)) * (DV * MM * 2);   // uniform
    const float* wsw = ws_w + (size_t)l * DV * DV;                    // uniform
    const float* wsb = ws_b + (size_t)l * DV;
    float oacc = FINAL ? q_b[0] : 0.f;

    #pragma unroll 4
    for (int co = 0; co < DV; ++co) {
        float acc = wsb[co];
        #pragma unroll
        for (int ci = 0; ci < DV; ++ci)
            acc += wsw[co * DV + ci] * hval[ci];          // s_load weights
        #pragma unroll
        for (int ky = 0; ky < MM; ++ky)
            acc += gp[co * (MM * 2) + 2 * ky]     * cs[ky]
                 - gp[co * (MM * 2) + 2 * ky + 1] * sn[ky];  // s_load g
        if (FINAL) oacc += q_w[co] * acc;
        else       hb[(size_t)co * SS * SS] = fmaxf(acc, 0.f);
    }
    if (FINAL) out[((size_t)b * SS + iy) * SS + tid] = oacc;
}

extern "C" void kernel_launch(void* const* d_in, const int* in_sizes, int n_in,
                              void* d_out, int out_size, void* d_ws, size_t ws_size,
                              hipStream_t stream)
{
    const float* x    = (const float*)d_in[0];
    const float* p_w  = (const float*)d_in[1];
    const float* p_b  = (const float*)d_in[2];
    const float* ws_w = (const float*)d_in[3];
    const float* ws_b = (const float*)d_in[4];
    const float* w1r  = (const float*)d_in[5];
    const float* w1i  = (const float*)d_in[6];
    const float* w2r  = (const float*)d_in[7];
    const float* w2i  = (const float*)d_in[8];
    const float* q_w  = (const float*)d_in[9];
    const float* q_b  = (const float*)d_in[10];
    float* out = (float*)d_out;

    float* h   = (float*)d_ws;
    float* A   = h + (size_t)NB * DV * SS * SS;
    float* F   = A + (size_t)NB * MM * DV * SS * 2;
    float* g   = F + (size_t)NB * MM * DV * MK * 2;
    float* twT = g + (size_t)NB * SS * DV * MM * 2;

    dim3 blk(256);
    k_twinit<<<1, blk, 0, stream>>>(twT);
    k_lift<<<NB * SS, blk, 0, stream>>>(x, p_w, p_b, h);
    for (int l = 0; l < LL; ++l) {
        k_rowdft<<<NB * DV, blk, 0, stream>>>(h, twT, A);
        k_mix<<<NB * MM, blk, 0, stream>>>(A, w1r, w1i, w2r, w2i, F, l);
        k_inv1<<<NB * SS, dim3(384), 0, stream>>>(F, g);
        if (l < LL - 1)
            k_pt<0><<<NB * SS, blk, 0, stream>>>(h, g, ws_w, ws_b,
                                                 nullptr, nullptr, nullptr, l);
        else
            k_pt<1><<<NB * SS, blk, 0, stream>>>(h, g, ws_w, ws_b,
                                                 q_w, q_b, out, l);
    }
}

// Round 7
// 871.883 us; speedup vs baseline: 1.3743x; 1.0792x over previous
//
#include <hip/hip_runtime.h>
#include <math.h>

#define NB 16    // batch
#define SS 256   // spatial size (H = W = 256)
#define DV 32    // channels
#define MM 12    // w-dim (j) modes kept
#define MK 24    // h-dim (iy) modes kept (0..11 and 244..255)
#define LL 4     // layers
#define TWO_PI_N 0.024543692606170259679f   // 2*pi/256

// Workspace (floats):
//   h   : [NB][DV][SS][SS]            134 MB, in-place per layer
//   A   : [NB][MM][DV][SS(iy)][2]     12.6 MB  (row-DFT of h)
//   F   : [NB][MM][DV][MK][2]          1.2 MB  (mixed spectral coeffs, pre-scaled)
//   g   : [NB][SS(iy)][MM][DV][2]     12.6 MB  (per-row spectral coeffs)
//   twT : [SS][MM][2]                  24 KB   (cos, -sin) of 2*pi*ky*j/256
//   wT  : [LL][ci][co]                 16 KB   (transposed conv weights)

// --------------------------------------------- setup: twiddle table + weight^T
__global__ __launch_bounds__(256) void k_prep(const float* __restrict__ ws_w,
        float* __restrict__ twT, float* __restrict__ wT)
{
    int j = threadIdx.x;
    #pragma unroll
    for (int k = 0; k < MM; ++k) {
        float ang = TWO_PI_N * (float)((k * j) & 255);
        float s, c; sincosf(ang, &s, &c);
        twT[j * (MM * 2) + 2 * k]     = c;
        twT[j * (MM * 2) + 2 * k + 1] = -s;
    }
    for (int idx = threadIdx.x; idx < LL * DV * DV; idx += 256) {
        int l = idx >> 10, rem = idx & 1023, co = rem >> 5, ci = rem & 31;
        wT[(l * DV + ci) * DV + co] = ws_w[(l * DV + co) * DV + ci];
    }
}

// ---------------------------------------------------------------- lifting
// grid = NB*64; block = 4 rows, one wave per row, 4 px/thread (float4).
__global__ __launch_bounds__(256) void k_lift(const float* __restrict__ x,
        const float* __restrict__ p_w, const float* __restrict__ p_b,
        float* __restrict__ h)
{
    int tid = threadIdx.x;
    int lane = tid & 63;
    int w = __builtin_amdgcn_readfirstlane(tid >> 6);
    int b  = blockIdx.x >> 6;
    int iy = ((blockIdx.x & 63) << 2) + w;
    int j0 = lane << 2;

    float4 xv = *(const float4*)(x + ((size_t)(b * SS + iy)) * SS + j0);
    float gy = -1.f + 2.f * (float)iy * (1.f / 255.f);
    float4 gx;
    gx.x = -1.f + 2.f * (float)j0 * (1.f / 255.f);
    gx.y = gx.x + 2.f / 255.f; gx.z = gx.y + 2.f / 255.f; gx.w = gx.z + 2.f / 255.f;

    float* hb = h + ((size_t)b * DV * SS + iy) * SS + j0;
    #pragma unroll
    for (int c = 0; c < DV; ++c) {
        float w0 = p_w[3*c], w1 = p_w[3*c+1], w2 = p_w[3*c+2], bb = p_b[c];
        float4 v;
        v.x = w0 * xv.x + w1 * gy + w2 * gx.x + bb;
        v.y = w0 * xv.y + w1 * gy + w2 * gx.y + bb;
        v.z = w0 * xv.z + w1 * gy + w2 * gx.z + bb;
        v.w = w0 * xv.w + w1 * gy + w2 * gx.w + bb;
        *(float4*)(hb + (size_t)c * SS * SS) = v;
    }
}

// ------------------------------------------------- forward row (j) DFT, 12 modes
// (unchanged from round 6)
__global__ __launch_bounds__(256, 4) void k_rowdft(const float* __restrict__ h,
        const float* __restrict__ twT, float* __restrict__ A)
{
    int tid = threadIdx.x;
    int b = blockIdx.x >> 5, c = blockIdx.x & 31;

    const float4* hr = (const float4*)(h + ((size_t)blockIdx.x * SS + tid) * SS);
    float ar[MM], ai[MM];
    #pragma unroll
    for (int k = 0; k < MM; ++k) { ar[k] = 0.f; ai[k] = 0.f; }

    #pragma unroll 2
    for (int j4 = 0; j4 < 32; ++j4) {
        float4 va = hr[j4];
        float4 vb = hr[j4 + 32];
        float hp[4] = {va.x + vb.x, va.y + vb.y, va.z + vb.z, va.w + vb.w};
        float hm[4] = {va.x - vb.x, va.y - vb.y, va.z - vb.z, va.w - vb.w};
        #pragma unroll
        for (int u = 0; u < 4; ++u) {
            const float* twj = twT + (size_t)(4 * j4 + u) * (MM * 2);  // uniform
            #pragma unroll
            for (int k = 0; k < 6; ++k) {
                ar[2*k]   += hp[u] * twj[4*k];
                ai[2*k]   += hp[u] * twj[4*k + 1];
                ar[2*k+1] += hm[u] * twj[4*k + 2];
                ai[2*k+1] += hm[u] * twj[4*k + 3];
            }
        }
    }
    #pragma unroll
    for (int ky = 0; ky < MM; ++ky) {
        size_t o = ((((size_t)b * MM + ky) * DV + c) * SS + tid) * 2;
        float2 val; val.x = ar[ky]; val.y = ai[ky];
        *(float2*)&A[o] = val;
    }
}

// --------------------------- kx (iy) DFT + complex channel mix -> F (pre-scaled)
// (unchanged from round 6)
__global__ __launch_bounds__(256) void k_mix(const float* __restrict__ A,
        const float* __restrict__ w1r, const float* __restrict__ w1i,
        const float* __restrict__ w2r, const float* __restrict__ w2i,
        float* __restrict__ F, int l)
{
    __shared__ float twcs[SS * 2];
    __shared__ float Fin[DV][MK * 2 + 2];
    int tid = threadIdx.x;
    int b = blockIdx.x / MM, ky = blockIdx.x % MM;
    {
        float ang = TWO_PI_N * (float)tid;
        float s, c; sincosf(ang, &s, &c);
        twcs[2 * tid] = c; twcs[2 * tid + 1] = s;
    }
    __syncthreads();

    int c = tid >> 3, set = tid & 7;
    const float2* Ap = (const float2*)(A + ((((size_t)b * MM + ky) * DV + c) * SS) * 2);

    float fr[3], fi[3], pc[3], ps[3], sc[3], ssn[3];
    int f[3];
    #pragma unroll
    for (int k = 0; k < 3; ++k) {
        int m = set + 8 * k;
        f[k] = (m < MM) ? m : (232 + m);
        sc[k] = twcs[2 * f[k]]; ssn[k] = twcs[2 * f[k] + 1];
        fr[k] = fi[k] = 0.f; pc[k] = 1.f; ps[k] = 0.f;
    }
    for (int iy = 0; iy < SS; ++iy) {
        if ((iy & 63) == 0) {
            #pragma unroll
            for (int k = 0; k < 3; ++k) {
                int t = (f[k] * iy) & 255;
                pc[k] = twcs[2 * t]; ps[k] = twcs[2 * t + 1];
            }
        }
        float2 a = Ap[iy];
        #pragma unroll
        for (int k = 0; k < 3; ++k) {
            fr[k] += a.x * pc[k] + a.y * ps[k];
            fi[k] += a.y * pc[k] - a.x * ps[k];
            float np = pc[k] * sc[k] - ps[k] * ssn[k];
            float nq = pc[k] * ssn[k] + ps[k] * sc[k];
            pc[k] = np; ps[k] = nq;
        }
    }
    #pragma unroll
    for (int k = 0; k < 3; ++k) {
        int m = set + 8 * k;
        Fin[c][2 * m] = fr[k]; Fin[c][2 * m + 1] = fi[k];
    }
    __syncthreads();

    int o = c;
    float scale = ((ky == 0) ? 1.0f : 2.0f) * (1.0f / 65536.0f);
    #pragma unroll
    for (int k = 0; k < 3; ++k) {
        int m = set + 8 * k;
        const float* Wr; const float* Wi; int xm;
        if (m < MM) { Wr = w1r; Wi = w1i; xm = m; }
        else        { Wr = w2r; Wi = w2i; xm = m - MM; }
        float orr = 0.f, oii = 0.f;
        for (int i = 0; i < DV; ++i) {
            float gr = Fin[i][2 * m], gi = Fin[i][2 * m + 1];
            size_t wi = ((size_t)(l * DV + i) * DV + o) * (MM * MM) + xm * MM + ky;
            float wr = Wr[wi], wim = Wi[wi];
            orr += gr * wr - gi * wim;
            oii += gr * wim + gi * wr;
        }
        size_t off = ((((size_t)b * MM + ky) * DV + o) * MK + m) * 2;
        F[off] = orr * scale; F[off + 1] = oii * scale;
    }
}

// -------------------- inverse iy-DFT: F -> g[b][iy][ky][co][2]
// block = (b,iy), 384 threads: ky = tid>>5, co = tid&31 -> writes contiguous.
__global__ __launch_bounds__(384) void k_inv1(const float* __restrict__ F,
        float* __restrict__ g)
{
    __shared__ float itw[MK * 2];
    int tid = threadIdx.x;
    int b = blockIdx.x >> 8, iy = blockIdx.x & 255;
    if (tid < MK) {
        int f = (tid < MM) ? tid : (232 + tid);
        float ang = TWO_PI_N * (float)((f * iy) & 255);
        float s, c; sincosf(ang, &s, &c);
        itw[2 * tid] = c; itw[2 * tid + 1] = s;
    }
    __syncthreads();

    int ky = tid >> 5, co = tid & 31;
    const float2* Fp = (const float2*)(F + ((((size_t)b * MM + ky) * DV + co) * MK) * 2);
    float gr = 0.f, gi = 0.f;
    #pragma unroll
    for (int m = 0; m < MK; ++m) {
        float2 fv = Fp[m];
        float ic = itw[2 * m], is = itw[2 * m + 1];
        gr += fv.x * ic - fv.y * is;
        gi += fv.x * is + fv.y * ic;
    }
    size_t o = (((size_t)(b * SS + iy)) * MM + ky) * (DV * 2) + 2 * co;
    g[o] = gr; g[o + 1] = gi;
}

// ----------------- pointwise: h = relu(conv1x1(h) + invDFT(F)), in place.
// grid = NB*64; block = 4 rows, one WAVE per row, 4 px/thread (float4).
// No LDS, no barriers. acc4[co] resident (128 VGPR); h streamed ci-outer with
// 1KB-burst float4 loads; weights/g/biases via wave-uniform s_load.
template<int FINAL>
__global__ __launch_bounds__(256, 2) void k_pt(float* __restrict__ h,
        const float* __restrict__ g, const float* __restrict__ wT,
        const float* __restrict__ ws_b, const float* __restrict__ q_w,
        const float* __restrict__ q_b, float* __restrict__ out, int l)
{
    int tid = threadIdx.x;
    int lane = tid & 63;
    int w = __builtin_amdgcn_readfirstlane(tid >> 6);
    int b  = blockIdx.x >> 6;
    int iy = ((blockIdx.x & 63) << 2) + w;
    int j0 = lane << 2;

    float* hb = h + ((size_t)b * DV * SS + iy) * SS + j0;
    const float* wt  = wT + (size_t)l * DV * DV;     // [ci][co], uniform
    const float* wsb = ws_b + (size_t)l * DV;

    float4 acc[DV];
    #pragma unroll
    for (int co = 0; co < DV; ++co) {
        float bv = wsb[co];
        acc[co].x = bv; acc[co].y = bv; acc[co].z = bv; acc[co].w = bv;
    }

    // conv1x1: stream input channels, 1KB-burst loads
    #pragma unroll 4
    for (int ci = 0; ci < DV; ++ci) {
        float4 hv = *(const float4*)(hb + (size_t)ci * SS * SS);
        const float* wc = wt + ci * DV;              // 32 contiguous s_loads
        #pragma unroll
        for (int co = 0; co < DV; ++co) {
            float wv = wc[co];
            acc[co].x += wv * hv.x; acc[co].y += wv * hv.y;
            acc[co].z += wv * hv.z; acc[co].w += wv * hv.w;
        }
    }

    // spectral: + sum_ky Re(G[co][ky] e^{+i 2pi ky j/256})
    const float* gp = g + ((size_t)(b * SS + iy)) * (MM * DV * 2);  // uniform
    #pragma unroll 2
    for (int ky = 0; ky < MM; ++ky) {
        float s0, c0, st, ct;
        sincosf(TWO_PI_N * (float)((ky * j0) & 255), &s0, &c0);
        sincosf(TWO_PI_N * (float)ky, &st, &ct);
        float cs[4], sn[4];
        cs[0] = c0; sn[0] = s0;
        #pragma unroll
        for (int u = 1; u < 4; ++u) {
            float nc = cs[u-1] * ct - sn[u-1] * st;
            float ns = sn[u-1] * ct + cs[u-1] * st;
            cs[u] = nc; sn[u] = ns;
        }
        const float* Gk = gp + ky * (DV * 2);        // 64 contiguous s_loads
        #pragma unroll
        for (int co = 0; co < DV; ++co) {
            float gr = Gk[2 * co], gi = Gk[2 * co + 1];
            acc[co].x += gr * cs[0] - gi * sn[0];
            acc[co].y += gr * cs[1] - gi * sn[1];
            acc[co].z += gr * cs[2] - gi * sn[2];
            acc[co].w += gr * cs[3] - gi * sn[3];
        }
    }

    if (FINAL) {
        float qb = q_b[0];
        float4 o4; o4.x = qb; o4.y = qb; o4.z = qb; o4.w = qb;
        #pragma unroll
        for (int co = 0; co < DV; ++co) {
            float qv = q_w[co];
            o4.x += qv * acc[co].x; o4.y += qv * acc[co].y;
            o4.z += qv * acc[co].z; o4.w += qv * acc[co].w;
        }
        *(float4*)(out + ((size_t)(b * SS + iy)) * SS + j0) = o4;
    } else {
        #pragma unroll
        for (int co = 0; co < DV; ++co) {
            float4 v;
            v.x = fmaxf(acc[co].x, 0.f); v.y = fmaxf(acc[co].y, 0.f);
            v.z = fmaxf(acc[co].z, 0.f); v.w = fmaxf(acc[co].w, 0.f);
            *(float4*)(hb + (size_t)co * SS * SS) = v;
        }
    }
}

extern "C" void kernel_launch(void* const* d_in, const int* in_sizes, int n_in,
                              void* d_out, int out_size, void* d_ws, size_t ws_size,
                              hipStream_t stream)
{
    const float* x    = (const float*)d_in[0];
    const float* p_w  = (const float*)d_in[1];
    const float* p_b  = (const float*)d_in[2];
    const float* ws_w = (const float*)d_in[3];
    const float* ws_b = (const float*)d_in[4];
    const float* w1r  = (const float*)d_in[5];
    const float* w1i  = (const float*)d_in[6];
    const float* w2r  = (const float*)d_in[7];
    const float* w2i  = (const float*)d_in[8];
    const float* q_w  = (const float*)d_in[9];
    const float* q_b  = (const float*)d_in[10];
    float* out = (float*)d_out;

    float* h   = (float*)d_ws;
    float* A   = h + (size_t)NB * DV * SS * SS;
    float* F   = A + (size_t)NB * MM * DV * SS * 2;
    float* g   = F + (size_t)NB * MM * DV * MK * 2;
    float* twT = g + (size_t)NB * SS * MM * DV * 2;
    float* wT  = twT + (size_t)SS * MM * 2;

    dim3 blk(256);
    k_prep<<<1, blk, 0, stream>>>(ws_w, twT, wT);
    k_lift<<<NB * 64, blk, 0, stream>>>(x, p_w, p_b, h);
    for (int l = 0; l < LL; ++l) {
        k_rowdft<<<NB * DV, blk, 0, stream>>>(h, twT, A);
        k_mix<<<NB * MM, blk, 0, stream>>>(A, w1r, w1i, w2r, w2i, F, l);
        k_inv1<<<NB * SS, dim3(384), 0, stream>>>(F, g);
        if (l < LL - 1)
            k_pt<0><<<NB * 64, blk, 0, stream>>>(h, g, wT, ws_b,
                                                 nullptr, nullptr, nullptr, l);
        else
            k_pt<1><<<NB * 64, blk, 0, stream>>>(h, g, wT, ws_b,
                                                 q_w, q_b, out, l);
    }
}